// Round 1
// baseline (209.775 us; speedup 1.0000x reference)
//
#include <hip/hip_runtime.h>

// Problem constants (fixed by reference setup_inputs)
#define B_    4
#define C_    128
#define H_    64
#define W_    64
#define CO_   128
#define K_    9
#define DG_   2
#define HW_   4096      // H*W == Ho*Wo
#define CK_   1152      // C_*K_
#define PIX_  32        // pixels per block tile
#define CT_   16        // channels per chunk
#define CKT_  144       // CT_*K_
#define NCHUNK_ 8       // C_/CT_

// Transposed weight: wT[ck][co] = w[co][ck]. Static device buffer so we don't
// depend on ws_size. Recomputed every launch (no cross-call state).
__device__ __align__(16) float g_wT[CK_ * CO_];

__global__ void transpose_w_kernel(const float* __restrict__ w) {
    int lin = blockIdx.x * 256 + threadIdx.x;   // 1152*128 = 147456 = 576 * 256
    int ck = lin >> 7;
    int co = lin & 127;
    g_wT[lin] = w[co * CK_ + ck];
}

__global__ __launch_bounds__(256) void mdcn_fused_kernel(
    const float* __restrict__ x,
    const float* __restrict__ offset,
    const float* __restrict__ mask,
    const float* __restrict__ bias,
    float* __restrict__ out)
{
    // Block: one batch b, one tile of 32 consecutive output pixels, all 128 Cout.
    const int bid = blockIdx.x;          // 512 blocks
    const int b = bid >> 7;              // /128
    const int pix_base = (bid & 127) * PIX_;
    const int tid = threadIdx.x;

    // Bilinear descriptors: (g,k,pixel-local) -> 4 gather indices + 4 weights
    __shared__ __align__(16) int   s_idx4[DG_ * K_ * PIX_ * 4];  // 9216 B
    __shared__ __align__(16) float s_wt4 [DG_ * K_ * PIX_ * 4];  // 9216 B
    __shared__ __align__(16) float s_col [CKT_ * PIX_];          // 18432 B

    // ---- Phase A: sampling descriptors (576 items) ----
    for (int it = tid; it < DG_ * K_ * PIX_; it += 256) {
        const int pl = it & 31;
        const int gk = it >> 5;          // g*9 + k
        const int g  = gk / 9;
        const int k  = gk - g * 9;
        const int ky = k / 3;
        const int kx = k - ky * 3;
        const int pix = pix_base + pl;
        const int ho = pix >> 6;
        const int wo = pix & 63;

        const size_t offc = (size_t)(b * 36 + g * 18 + k * 2);
        const float py = offset[offc * HW_ + pix]       + (float)(ho - 1 + ky);
        const float px = offset[(offc + 1) * HW_ + pix] + (float)(wo - 1 + kx);
        const float m  = mask[(size_t)(b * 18 + g * 9 + k) * HW_ + pix];

        const float y0f = floorf(py);
        const float x0f = floorf(px);
        const float ly = py - y0f;
        const float lx = px - x0f;
        const int y0 = (int)y0f;
        const int x0 = (int)x0f;

        const float w00 = (1.0f - ly) * (1.0f - lx) * m;
        const float w01 = (1.0f - ly) * lx * m;
        const float w10 = ly * (1.0f - lx) * m;
        const float w11 = ly * lx * m;

        int   idx[4];
        float wt[4];
        const int ys[4] = { y0, y0, y0 + 1, y0 + 1 };
        const int xs[4] = { x0, x0 + 1, x0, x0 + 1 };
        const float ws[4] = { w00, w01, w10, w11 };
#pragma unroll
        for (int c2 = 0; c2 < 4; ++c2) {
            const bool v = (ys[c2] >= 0) & (ys[c2] < H_) & (xs[c2] >= 0) & (xs[c2] < W_);
            idx[c2] = v ? (ys[c2] * W_ + xs[c2]) : 0;
            wt[c2]  = v ? ws[c2] : 0.0f;
        }
        *(int4*)&s_idx4[it * 4]  = make_int4(idx[0], idx[1], idx[2], idx[3]);
        *(float4*)&s_wt4[it * 4] = make_float4(wt[0], wt[1], wt[2], wt[3]);
    }
    __syncthreads();

    // ---- Phase B: chunked col staging + register-tile GEMM ----
    const int co0  = (tid & 31) * 4;     // 4 consecutive output channels
    const int pix0 = (tid >> 5) * 4;     // 4 consecutive pixels (local)

    float acc[4][4];
#pragma unroll
    for (int i = 0; i < 4; ++i)
#pragma unroll
        for (int j = 0; j < 4; ++j) acc[i][j] = 0.0f;

    const float* __restrict__ xb = x + (size_t)b * C_ * HW_;

    for (int ch = 0; ch < NCHUNK_; ++ch) {
        const int c0 = ch * CT_;

        // Stage col tile: 144 ck x 32 pix (18 samples/thread)
        for (int lin = tid; lin < CKT_ * PIX_; lin += 256) {
            const int ckl = lin >> 5;
            const int pl  = lin & 31;
            const int cl  = ckl / 9;                 // local channel
            const int k   = ckl - cl * 9;
            const int c   = c0 + cl;
            const int g   = c >> 6;                  // deform group
            const int pidx = ((g * 9 + k) * PIX_ + pl) * 4;
            const int4   idx = *(const int4*)&s_idx4[pidx];
            const float4 wt  = *(const float4*)&s_wt4[pidx];
            const float* __restrict__ xc = xb + (size_t)c * HW_;
            const float v = wt.x * xc[idx.x] + wt.y * xc[idx.y]
                          + wt.z * xc[idx.z] + wt.w * xc[idx.w];
            s_col[lin] = v;
        }
        __syncthreads();

        const float* __restrict__ wTp = g_wT + (size_t)(c0 * 9) * CO_ + co0;
#pragma unroll 4
        for (int ckl = 0; ckl < CKT_; ++ckl) {
            const float4 cv = *(const float4*)&s_col[ckl * PIX_ + pix0];
            const float4 wv = *(const float4*)(wTp + (size_t)ckl * CO_);
            acc[0][0] = fmaf(wv.x, cv.x, acc[0][0]);
            acc[0][1] = fmaf(wv.x, cv.y, acc[0][1]);
            acc[0][2] = fmaf(wv.x, cv.z, acc[0][2]);
            acc[0][3] = fmaf(wv.x, cv.w, acc[0][3]);
            acc[1][0] = fmaf(wv.y, cv.x, acc[1][0]);
            acc[1][1] = fmaf(wv.y, cv.y, acc[1][1]);
            acc[1][2] = fmaf(wv.y, cv.z, acc[1][2]);
            acc[1][3] = fmaf(wv.y, cv.w, acc[1][3]);
            acc[2][0] = fmaf(wv.z, cv.x, acc[2][0]);
            acc[2][1] = fmaf(wv.z, cv.y, acc[2][1]);
            acc[2][2] = fmaf(wv.z, cv.z, acc[2][2]);
            acc[2][3] = fmaf(wv.z, cv.w, acc[2][3]);
            acc[3][0] = fmaf(wv.w, cv.x, acc[3][0]);
            acc[3][1] = fmaf(wv.w, cv.y, acc[3][1]);
            acc[3][2] = fmaf(wv.w, cv.z, acc[3][2]);
            acc[3][3] = fmaf(wv.w, cv.w, acc[3][3]);
        }
        __syncthreads();
    }

    // ---- Epilogue: bias + store (float4 per co row) ----
#pragma unroll
    for (int i = 0; i < 4; ++i) {
        const float bi = bias[co0 + i];
        float4 o;
        o.x = acc[i][0] + bi;
        o.y = acc[i][1] + bi;
        o.z = acc[i][2] + bi;
        o.w = acc[i][3] + bi;
        *(float4*)&out[(size_t)(b * CO_ + co0 + i) * HW_ + pix_base + pix0] = o;
    }
}

extern "C" void kernel_launch(void* const* d_in, const int* in_sizes, int n_in,
                              void* d_out, int out_size, void* d_ws, size_t ws_size,
                              hipStream_t stream) {
    const float* x      = (const float*)d_in[0];
    const float* offset = (const float*)d_in[1];
    const float* mask   = (const float*)d_in[2];
    const float* weight = (const float*)d_in[3];
    const float* bias   = (const float*)d_in[4];
    float* out = (float*)d_out;

    hipLaunchKernelGGL(transpose_w_kernel, dim3(CK_ * CO_ / 256), dim3(256), 0, stream, weight);
    hipLaunchKernelGGL(mdcn_fused_kernel, dim3(B_ * (HW_ / PIX_)), dim3(256), 0, stream,
                       x, offset, mask, bias, out);
}

// Round 2
// 156.743 us; speedup vs baseline: 1.3383x; 1.3383x over previous
//
#include <hip/hip_runtime.h>

// Problem constants (fixed by reference setup_inputs)
#define B_    4
#define C_    128
#define H_    64
#define W_    64
#define CO_   128
#define K_    9
#define DG_   2
#define HW_   4096      // H*W == Ho*Wo
#define CK_   1152      // C_*K_
#define PIX_  16        // pixels per block tile -> 1024 blocks (4/CU)
#define BK_   128       // ck per chunk
#define NCHUNK_ 9       // 1152/128
#define CSTR_ 136       // col LDS leading stride in ushort (BK_+8 pad -> 2-way banks only)

typedef __attribute__((ext_vector_type(8))) short  short8;
typedef __attribute__((ext_vector_type(4))) float  floatx4;

// bf16 weight copy, [co][ck] row-major (A-operand wants 8 consecutive k per lane).
__device__ __align__(16) unsigned short g_wbf[CK_ * CO_];

__device__ __forceinline__ unsigned short f32_to_bf16(float f) {
    // round-to-nearest-even (inputs finite)
    unsigned int u = __float_as_uint(f);
    u += 0x7FFFu + ((u >> 16) & 1u);
    return (unsigned short)(u >> 16);
}

__global__ void prep_w_kernel(const float* __restrict__ w) {
    int lin = blockIdx.x * 256 + threadIdx.x;   // 147456 / 256 = 576 blocks
    g_wbf[lin] = f32_to_bf16(w[lin]);
}

__global__ __launch_bounds__(256) void mdcn_mfma_kernel(
    const float* __restrict__ x,
    const float* __restrict__ offset,
    const float* __restrict__ mask,
    const float* __restrict__ bias,
    float* __restrict__ out)
{
    const int bid = blockIdx.x;          // 1024 blocks
    const int b = bid >> 8;              // /256 tiles per batch
    const int pix_base = (bid & 255) * PIX_;
    const int tid = threadIdx.x;

    // Bilinear descriptors for this pixel tile: (g,k,pl) -> 4 indices + 4 mask-folded weights
    __shared__ __align__(16) int            s_idx4[DG_ * K_ * PIX_ * 4];  // 4608 B
    __shared__ __align__(16) float          s_wt4 [DG_ * K_ * PIX_ * 4];  // 4608 B
    __shared__ __align__(16) unsigned short s_colb[PIX_ * CSTR_];         // 4352 B bf16 col tile

    // ---- Phase A: sampling descriptors (288 items) ----
    for (int it = tid; it < DG_ * K_ * PIX_; it += 256) {
        const int pl = it & (PIX_ - 1);
        const int gk = it / PIX_;            // g*9 + k
        const int g  = gk / 9;
        const int k  = gk - g * 9;
        const int ky = k / 3;
        const int kx = k - ky * 3;
        const int pix = pix_base + pl;
        const int ho = pix >> 6;
        const int wo = pix & 63;

        const size_t offc = (size_t)(b * 36 + g * 18 + k * 2);
        const float py = offset[offc * HW_ + pix]       + (float)(ho - 1 + ky);
        const float px = offset[(offc + 1) * HW_ + pix] + (float)(wo - 1 + kx);
        const float m  = mask[(size_t)(b * 18 + g * 9 + k) * HW_ + pix];

        const float y0f = floorf(py);
        const float x0f = floorf(px);
        const float ly = py - y0f;
        const float lx = px - x0f;
        const int y0 = (int)y0f;
        const int x0 = (int)x0f;

        const float w00 = (1.0f - ly) * (1.0f - lx) * m;
        const float w01 = (1.0f - ly) * lx * m;
        const float w10 = ly * (1.0f - lx) * m;
        const float w11 = ly * lx * m;

        int   idx[4];
        float wt[4];
        const int ys[4] = { y0, y0, y0 + 1, y0 + 1 };
        const int xs[4] = { x0, x0 + 1, x0, x0 + 1 };
        const float ws[4] = { w00, w01, w10, w11 };
#pragma unroll
        for (int c2 = 0; c2 < 4; ++c2) {
            const bool v = (ys[c2] >= 0) & (ys[c2] < H_) & (xs[c2] >= 0) & (xs[c2] < W_);
            idx[c2] = v ? (ys[c2] * W_ + xs[c2]) : 0;
            wt[c2]  = v ? ws[c2] : 0.0f;
        }
        *(int4*)&s_idx4[it * 4]  = make_int4(idx[0], idx[1], idx[2], idx[3]);
        *(float4*)&s_wt4[it * 4] = make_float4(wt[0], wt[1], wt[2], wt[3]);
    }
    __syncthreads();

    // ---- Phase B: chunked bf16 col staging + MFMA ----
    const int lane = tid & 63;
    const int wv   = tid >> 6;          // wave 0..3 -> co range [wv*32, wv*32+32)
    const int quad = lane >> 4;
    const int l15  = lane & 15;

    floatx4 acc0 = {0.f, 0.f, 0.f, 0.f};
    floatx4 acc1 = {0.f, 0.f, 0.f, 0.f};

    // A-frag base pointers: lane holds w[co = base + l15][k = ck + quad*8 .. +7]
    const unsigned short* __restrict__ wr0 = g_wbf + (size_t)(wv * 32 + l15) * CK_ + quad * 8;
    const unsigned short* __restrict__ wr1 = wr0 + (size_t)16 * CK_;

    const float* __restrict__ xb = x + (size_t)b * C_ * HW_;
    const int pl   = tid & 15;          // staging: one pixel per thread
    const int ckl0 = (tid >> 4) * 8;    // 8 consecutive local ck per thread

    for (int ch = 0; ch < NCHUNK_; ++ch) {
        const int ckb = ch * BK_;

        // Stage 8 col values (fp32 bilinear sample -> bf16)
        short8 sv;
#pragma unroll
        for (int i = 0; i < 8; ++i) {
            const int ckg = ckb + ckl0 + i;
            const int c = ckg / 9;
            const int k = ckg - c * 9;
            const int g = c >> 6;
            const int di = (g * 9 + k) * PIX_ + pl;
            const int4   idx = ((const int4*)s_idx4)[di];
            const float4 wt  = ((const float4*)s_wt4)[di];
            const float* __restrict__ xc = xb + (size_t)c * HW_;
            const float v = wt.x * xc[idx.x] + wt.y * xc[idx.y]
                          + wt.z * xc[idx.z] + wt.w * xc[idx.w];
            sv[i] = (short)f32_to_bf16(v);
        }
        *(short8*)&s_colb[pl * CSTR_ + ckl0] = sv;
        __syncthreads();

        // 4 K-steps of 32: B from LDS, A from L2-resident bf16 weights
#pragma unroll
        for (int ks = 0; ks < 4; ++ks) {
            const short8 bf = *(const short8*)&s_colb[l15 * CSTR_ + ks * 32 + quad * 8];
            const short8 a0 = *(const short8*)(wr0 + ckb + ks * 32);
            const short8 a1 = *(const short8*)(wr1 + ckb + ks * 32);
            acc0 = __builtin_amdgcn_mfma_f32_16x16x32_bf16(a0, bf, acc0, 0, 0, 0);
            acc1 = __builtin_amdgcn_mfma_f32_16x16x32_bf16(a1, bf, acc1, 0, 0, 0);
        }
        __syncthreads();
    }

    // ---- Epilogue: C/D layout col=lane&15 (pixel), row=quad*4+reg (co) ----
#pragma unroll
    for (int mt = 0; mt < 2; ++mt) {
        const floatx4 a = mt ? acc1 : acc0;
        const int cobase = wv * 32 + mt * 16 + quad * 4;
#pragma unroll
        for (int r = 0; r < 4; ++r) {
            const int co = cobase + r;
            out[(size_t)(b * CO_ + co) * HW_ + pix_base + l15] = a[r] + bias[co];
        }
    }
}

extern "C" void kernel_launch(void* const* d_in, const int* in_sizes, int n_in,
                              void* d_out, int out_size, void* d_ws, size_t ws_size,
                              hipStream_t stream) {
    const float* x      = (const float*)d_in[0];
    const float* offset = (const float*)d_in[1];
    const float* mask   = (const float*)d_in[2];
    const float* weight = (const float*)d_in[3];
    const float* bias   = (const float*)d_in[4];
    float* out = (float*)d_out;

    hipLaunchKernelGGL(prep_w_kernel, dim3(CK_ * CO_ / 256), dim3(256), 0, stream, weight);
    hipLaunchKernelGGL(mdcn_mfma_kernel, dim3(B_ * (HW_ / PIX_)), dim3(256), 0, stream,
                       x, offset, mask, bias, out);
}